// Round 1
// baseline (2193.337 us; speedup 1.0000x reference)
//
#include <hip/hip_runtime.h>

#define H4 128     // hidden
#define EE 768     // embedding
#define NL 20      // layers
#define BB 64      // batch
#define TT 512     // seq len
#define G4 512     // 4*H
#define MB 8       // batch per group
#define NBG 8      // batch groups
#define RING 16    // ring slots per layer

typedef _Float16 v8h __attribute__((ext_vector_type(8)));
typedef _Float16 v4h __attribute__((ext_vector_type(4)));
typedef float v4f __attribute__((ext_vector_type(4)));
typedef unsigned int v4u __attribute__((ext_vector_type(4)));
typedef unsigned int v2u __attribute__((ext_vector_type(2)));

#if defined(__has_builtin)
#if __has_builtin(__builtin_amdgcn_exp2f) && __has_builtin(__builtin_amdgcn_rcpf)
#define EXP2F __builtin_amdgcn_exp2f
#define RCPF  __builtin_amdgcn_rcpf
#endif
#endif
#ifndef EXP2F
#define EXP2F exp2f
#define RCPF(x) (1.0f/(x))
#endif

__device__ __forceinline__ float fast_sig(float x) {
  float e = EXP2F(-1.44269504f * x);
  return RCPF(1.0f + e);
}
__device__ __forceinline__ float fast_tanh(float x) {
  float e = EXP2F(2.88539008f * x);   // e^(2x)
  return 1.0f - 2.0f * RCPF(1.0f + e);
}

// ---------------- prep: fp16 weights, combined bias, zero flags ----------------
__global__ __launch_bounds__(256) void prep_kernel(
    const float* __restrict__ Wih0, const float* __restrict__ Whh0,
    const float* __restrict__ bih,  const float* __restrict__ bhh,
    const float* __restrict__ Wih,  const float* __restrict__ Whh,
    _Float16* __restrict__ W0h, _Float16* __restrict__ Wc,
    float* __restrict__ biasc, unsigned* __restrict__ flags)
{
  long idx = (long)blockIdx.x * 256 + threadIdx.x;
  const long NWC = (long)NL * G4 * 256;   // 2,621,440
  const long NW0 = (long)G4 * EE;         // 393,216
  const long NBI = (long)NL * G4;         // 10,240
  if (idx < NWC) {
    int l = (int)(idx >> 17);
    int rem = (int)(idx & 131071);
    int n = rem >> 8, kk = rem & 255;
    float v;
    if (l == 0) v = (kk < 128) ? 0.0f : Whh0[n * H4 + kk - 128];
    else v = (kk < 128) ? Wih[((long)(l-1) * G4 + n) * H4 + kk]
                        : Whh[((long)(l-1) * G4 + n) * H4 + kk - 128];
    Wc[idx] = (_Float16)v;
  } else if ((idx -= NWC) < NW0) {
    W0h[idx] = (_Float16)Wih0[idx];
  } else if ((idx -= NW0) < NBI) {
    int l = (int)(idx >> 9), n = (int)(idx & 511);
    biasc[idx] = (l == 0) ? 0.0f : (bih[(l-1) * G4 + n] + bhh[(l-1) * G4 + n]);
  } else if ((idx -= NBI) < 256) {
    flags[idx] = 0u;
  }
}

// ---------------- layer-0 input projection GEMM: pre0[t][n][b] fp16 ----------------
// C[t*64+b][n] = sum_e x[b][t][e]*Wih0[n][e] + (bih0[n]+bhh0[n])
__global__ __launch_bounds__(512) void pre0_gemm(
    const float* __restrict__ x, const _Float16* __restrict__ W0h,
    const float* __restrict__ bih0, const float* __restrict__ bhh0,
    _Float16* __restrict__ pre0)
{
  __shared__ __align__(16) unsigned char smem[46080];
  _Float16* sA = (_Float16*)smem;             // [64][40]
  _Float16* sB = (_Float16*)(smem + 5120);    // [512][40]
  _Float16* sC = (_Float16*)smem;             // alias: [256][72] bounce
  int t = blockIdx.x;
  int tid = threadIdx.x;
  int w = tid >> 6, lane = tid & 63;
  int l15 = lane & 15, kb = lane >> 4;

  v4f acc[4][4];
#pragma unroll
  for (int mi = 0; mi < 4; ++mi)
#pragma unroll
    for (int ni = 0; ni < 4; ++ni) acc[mi][ni] = (v4f){0.f, 0.f, 0.f, 0.f};

  int bA = tid >> 3, kqA = tid & 7;
  const float* xp = x + ((long)bA * TT + t) * EE + kqA * 4;
  const _Float16* wp = W0h + (long)tid * EE;

  for (int k0 = 0; k0 < EE; k0 += 32) {
    float4 xv = *(const float4*)(xp + k0);
    v4h xh = { (_Float16)xv.x, (_Float16)xv.y, (_Float16)xv.z, (_Float16)xv.w };
    *(v4h*)&sA[bA * 40 + kqA * 4] = xh;
#pragma unroll
    for (int c = 0; c < 4; ++c)
      *(v8h*)&sB[tid * 40 + c * 8] = *(const v8h*)(wp + k0 + c * 8);
    __syncthreads();
#pragma unroll
    for (int mi = 0; mi < 4; ++mi) {
      v8h a = *(const v8h*)&sA[(16 * mi + l15) * 40 + kb * 8];
#pragma unroll
      for (int ni = 0; ni < 4; ++ni) {
        v8h b = *(const v8h*)&sB[(64 * w + 16 * ni + l15) * 40 + kb * 8];
        acc[mi][ni] = __builtin_amdgcn_mfma_f32_16x16x32_f16(a, b, acc[mi][ni], 0, 0, 0);
      }
    }
    __syncthreads();
  }

  // epilogue: two bounce rounds of 256 n-rows each -> pre0[t][n][b]
#pragma unroll
  for (int hh2 = 0; hh2 < 2; ++hh2) {
    __syncthreads();
    if ((w >> 2) == hh2) {
      int wl = w & 3;
#pragma unroll
      for (int ni = 0; ni < 4; ++ni) {
        int nloc = 64 * wl + 16 * ni + l15;
        int n = 256 * hh2 + nloc;
        float bia = bih0[n] + bhh0[n];
#pragma unroll
        for (int mi = 0; mi < 4; ++mi)
#pragma unroll
          for (int r = 0; r < 4; ++r)
            sC[nloc * 72 + 16 * mi + 4 * kb + r] = (_Float16)(acc[mi][ni][r] + bia);
      }
    }
    __syncthreads();
    int row = tid >> 1, part = tid & 1;
    _Float16* po = pre0 + ((long)t * G4 + 256 * hh2 + row) * 64 + part * 32;
#pragma unroll
    for (int c = 0; c < 4; ++c)
      *(v8h*)(po + c * 8) = *(const v8h*)&sC[row * 72 + part * 32 + c * 8];
  }
}

// ---------------- persistent pipelined LSTM ----------------
// 160 blocks: (layer l, batch-group bg). 512 threads = 8 waves, wave w owns
// hidden-unit strip j in [16w,16w+16) and all 4 gates for it; weights live in VGPRs.
__global__ __launch_bounds__(512) void lstm_pipe(
    const _Float16* __restrict__ pre0, const _Float16* __restrict__ Wc,
    const float* __restrict__ biasc, _Float16* __restrict__ yring,
    unsigned* __restrict__ flags, float* __restrict__ out)
{
  __shared__ _Float16 sA[16 * 264];   // A tile: rows=local batch(16, 8 valid), cols 0..127=y_in, 128..255=h
  int l = blockIdx.x >> 3, bg = blockIdx.x & 7;
  int tid = threadIdx.x, w = tid >> 6, lane = tid & 63;
  int l15 = lane & 15, kb = lane >> 4;
  int jloc = 16 * w + l15;            // global hidden index 0..127
  bool valid = (kb < 2);
  int b0 = 4 * (kb & 1);              // 0 or 4 for valid lanes

  // preload weight fragments (held in VGPRs for the whole kernel)
  v8h bw[4][8];
  const _Float16* wbase = Wc + (long)l * G4 * 256;
#pragma unroll
  for (int q = 0; q < 4; ++q)
#pragma unroll
    for (int ks = 0; ks < 8; ++ks)
      bw[q][ks] = *(const v8h*)(wbase + (long)(128 * q + jloc) * 256 + ks * 32 + kb * 8);

  float bias_q[4];
#pragma unroll
  for (int q = 0; q < 4; ++q)
    bias_q[q] = (l == 0) ? 0.0f : biasc[l * G4 + 128 * q + jloc];

  for (int i = tid; i < 16 * 264; i += 512) sA[i] = (_Float16)0.0f;

  v4f cst = (v4f){0.f, 0.f, 0.f, 0.f};
  const int myf = l * 8 + bg;
  _Float16* yout = yring + (long)(myf * RING) * 1024;
  const _Float16* yin = (l > 0) ? (yring + (long)((myf - 8) * RING) * 1024) : yring;

  __syncthreads();

  for (int t = 0; t < TT; ++t) {
    asm volatile("s_waitcnt vmcnt(0)" ::: "memory");  // own y stores of t-1 retired (visible at L3)
    __syncthreads();
    if (tid == 0) {
      if (t > 0)
        __hip_atomic_store(&flags[myf], (unsigned)t, __ATOMIC_RELAXED, __HIP_MEMORY_SCOPE_AGENT);
      if (l > 0)
        while (__hip_atomic_load(&flags[myf - 8], __ATOMIC_RELAXED, __HIP_MEMORY_SCOPE_AGENT) < (unsigned)(t + 1))
          __builtin_amdgcn_s_sleep(2);
      if (l < NL - 1 && t >= RING)
        while (__hip_atomic_load(&flags[myf + 8], __ATOMIC_RELAXED, __HIP_MEMORY_SCOPE_AGENT) < (unsigned)(t - RING + 1))
          __builtin_amdgcn_s_sleep(2);
    }
    __syncthreads();

    v4f acc[4];
#pragma unroll
    for (int q = 0; q < 4; ++q) acc[q] = (v4f){bias_q[q], bias_q[q], bias_q[q], bias_q[q]};

    if (l == 0) {
      const _Float16* pb = pre0 + (long)t * G4 * 64 + bg * 8 + (valid ? b0 : 0);
#pragma unroll
      for (int q = 0; q < 4; ++q) {
        v4h pv = *(const v4h*)(pb + (long)(128 * q + jloc) * 64);
#pragma unroll
        for (int r = 0; r < 4; ++r) acc[q][r] += (float)pv[r];
      }
    } else {
      if (tid < 128) {  // waves 0,1: stage y_in (device-coherent) into LDS cols 0..127
        const _Float16* src = yin + (long)(t & (RING - 1)) * 1024 + tid * 8;
        v4u v;
        asm volatile("global_load_dwordx4 %0, %1, off sc0 sc1\n\ts_waitcnt vmcnt(0)"
                     : "=v"(v) : "v"(src) : "memory");
        union { v4u u; _Float16 h[8]; } uu; uu.u = v;
#pragma unroll
        for (int b = 0; b < 8; ++b) sA[b * 264 + tid] = uu.h[b];
      }
    }
    __syncthreads();

    // MFMA over K (layer0: h-part only, ks 4..7)
#pragma unroll
    for (int ks = 0; ks < 8; ++ks) {
      if (l == 0 && ks < 4) continue;
      v8h a = *(const v8h*)&sA[l15 * 264 + ks * 32 + kb * 8];
#pragma unroll
      for (int q = 0; q < 4; ++q)
        acc[q] = __builtin_amdgcn_mfma_f32_16x16x32_f16(a, bw[q][ks], acc[q], 0, 0, 0);
    }

    // gates + cell update (register-only)
    _Float16 hh[4]; float hf[4];
#pragma unroll
    for (int r = 0; r < 4; ++r) {
      float i_ = fast_sig(acc[0][r]);
      float f_ = fast_sig(acc[1][r]);
      float g_ = fast_tanh(acc[2][r]);
      float o_ = fast_sig(acc[3][r]);
      float cn = f_ * cst[r] + i_ * g_;
      cst[r] = cn;
      float h_ = o_ * fast_tanh(cn);
      hf[r] = h_;
      hh[r] = (_Float16)h_;
    }

    __syncthreads();  // all waves done reading sA before h overwrite
    if (valid) {
#pragma unroll
      for (int r = 0; r < 4; ++r) sA[(b0 + r) * 264 + 128 + jloc] = hh[r];
      if (l < NL - 1) {
        union { v2u u; _Float16 h[4]; } pk;
#pragma unroll
        for (int r = 0; r < 4; ++r) pk.h[r] = hh[r];
        _Float16* dst = yout + (long)(t & (RING - 1)) * 1024 + jloc * 8 + b0;
        asm volatile("global_store_dwordx2 %0, %1, off sc0 sc1" :: "v"(dst), "v"(pk.u) : "memory");
      } else if (t == TT - 1) {
#pragma unroll
        for (int r = 0; r < 4; ++r) out[(bg * 8 + b0 + r) * H4 + jloc] = hf[r];
      }
    }
  }
  if (tid == 0)
    __hip_atomic_store(&flags[myf], (unsigned)TT, __ATOMIC_RELAXED, __HIP_MEMORY_SCOPE_AGENT);
}

extern "C" void kernel_launch(void* const* d_in, const int* in_sizes, int n_in,
                              void* d_out, int out_size, void* d_ws, size_t ws_size,
                              hipStream_t stream)
{
  const float* x    = (const float*)d_in[0];
  const float* Wih0 = (const float*)d_in[1];
  const float* Whh0 = (const float*)d_in[2];
  const float* bih0 = (const float*)d_in[3];
  const float* bhh0 = (const float*)d_in[4];
  const float* Wih  = (const float*)d_in[5];
  const float* Whh  = (const float*)d_in[6];
  const float* bih  = (const float*)d_in[7];
  const float* bhh  = (const float*)d_in[8];
  float* out = (float*)d_out;
  char* ws = (char*)d_ws;

  _Float16* pre0  = (_Float16*)(ws);              // 33,554,432 B
  _Float16* W0h   = (_Float16*)(ws + 33554432);   //    786,432 B
  _Float16* Wc    = (_Float16*)(ws + 34340864);   //  5,242,880 B
  float*    bc    = (float*)   (ws + 39583744);   //     40,960 B
  _Float16* yring = (_Float16*)(ws + 39624704);   //  5,242,880 B
  unsigned* flags = (unsigned*)(ws + 44867584);   //      1,024 B

  prep_kernel<<<11817, 256, 0, stream>>>(Wih0, Whh0, bih, bhh, Wih, Whh, W0h, Wc, bc, flags);
  pre0_gemm<<<TT, 512, 0, stream>>>(x, W0h, bih0, bhh0, pre0);
  lstm_pipe<<<NL * NBG, 512, 0, stream>>>(pre0, Wc, bc, yring, flags, out);
}

// Round 2
// 1150.260 us; speedup vs baseline: 1.9068x; 1.9068x over previous
//
#include <hip/hip_runtime.h>

#define H4 128     // hidden
#define EE 768     // embedding
#define NL 20      // layers
#define BB 64      // batch
#define TT 512     // seq len
#define G4 512     // 4*H
#define NBG 8      // batch groups
#define CK 16      // timesteps per chunk (handoff granularity)
#define NCH (TT/CK)
#define RC 2       // ring slots (chunks) per flow

typedef _Float16 v8h __attribute__((ext_vector_type(8)));
typedef _Float16 v4h __attribute__((ext_vector_type(4)));
typedef float v4f __attribute__((ext_vector_type(4)));
typedef unsigned int v4u __attribute__((ext_vector_type(4)));
typedef unsigned int v2u __attribute__((ext_vector_type(2)));

#if defined(__has_builtin)
#if __has_builtin(__builtin_amdgcn_exp2f) && __has_builtin(__builtin_amdgcn_rcpf)
#define EXP2F __builtin_amdgcn_exp2f
#define RCPF  __builtin_amdgcn_rcpf
#endif
#endif
#ifndef EXP2F
#define EXP2F exp2f
#define RCPF(x) (1.0f/(x))
#endif

__device__ __forceinline__ float fast_sig(float x) {
  float e = EXP2F(-1.44269504f * x);
  return RCPF(1.0f + e);
}
__device__ __forceinline__ float fast_tanh(float x) {
  float e = EXP2F(2.88539008f * x);   // e^(2x)
  return 1.0f - 2.0f * RCPF(1.0f + e);
}

// XOR swizzle: row-major [row][256B] tile, spreads the 16B units of a column
// across bank groups (m201 st-swizzle pattern). Bijective within each row.
__device__ __forceinline__ int swz(int row, int byteInRow) {
  return (row * 256 + byteInRow) ^ ((row & 7) << 4);
}

// ---------------- prep: fp16 weights, combined bias, zero flags ----------------
__global__ __launch_bounds__(256) void prep_kernel(
    const float* __restrict__ Wih0, const float* __restrict__ Whh0,
    const float* __restrict__ bih,  const float* __restrict__ bhh,
    const float* __restrict__ Wih,  const float* __restrict__ Whh,
    _Float16* __restrict__ W0h, _Float16* __restrict__ Wc,
    float* __restrict__ biasc, unsigned* __restrict__ flags)
{
  long idx = (long)blockIdx.x * 256 + threadIdx.x;
  const long NWC = (long)NL * G4 * 256;   // 2,621,440
  const long NW0 = (long)G4 * EE;         // 393,216
  const long NBI = (long)NL * G4;         // 10,240
  if (idx < NWC) {
    int l = (int)(idx >> 17);
    int rem = (int)(idx & 131071);
    int n = rem >> 8, kk = rem & 255;
    float v;
    if (l == 0) v = (kk < 128) ? 0.0f : Whh0[n * H4 + kk - 128];
    else v = (kk < 128) ? Wih[((long)(l-1) * G4 + n) * H4 + kk]
                        : Whh[((long)(l-1) * G4 + n) * H4 + kk - 128];
    Wc[idx] = (_Float16)v;
  } else if ((idx -= NWC) < NW0) {
    W0h[idx] = (_Float16)Wih0[idx];
  } else if ((idx -= NW0) < NBI) {
    int l = (int)(idx >> 9), n = (int)(idx & 511);
    biasc[idx] = (l == 0) ? 0.0f : (bih[(l-1) * G4 + n] + bhh[(l-1) * G4 + n]);
  } else if ((idx -= NBI) < 256) {
    flags[idx] = 0u;
  }
}

// ---------------- layer-0 input projection GEMM: pre0[t][n][b] fp16 ----------------
__global__ __launch_bounds__(512) void pre0_gemm(
    const float* __restrict__ x, const _Float16* __restrict__ W0h,
    const float* __restrict__ bih0, const float* __restrict__ bhh0,
    _Float16* __restrict__ pre0)
{
  __shared__ __align__(16) unsigned char smem[46080];
  _Float16* sA = (_Float16*)smem;             // [64][40]
  _Float16* sB = (_Float16*)(smem + 5120);    // [512][40]
  _Float16* sC = (_Float16*)smem;             // alias: [256][72] bounce
  int t = blockIdx.x;
  int tid = threadIdx.x;
  int w = tid >> 6, lane = tid & 63;
  int l15 = lane & 15, kb = lane >> 4;

  v4f acc[4][4];
#pragma unroll
  for (int mi = 0; mi < 4; ++mi)
#pragma unroll
    for (int ni = 0; ni < 4; ++ni) acc[mi][ni] = (v4f){0.f, 0.f, 0.f, 0.f};

  int bA = tid >> 3, kqA = tid & 7;
  const float* xp = x + ((long)bA * TT + t) * EE + kqA * 4;
  const _Float16* wp = W0h + (long)tid * EE;

  for (int k0 = 0; k0 < EE; k0 += 32) {
    float4 xv = *(const float4*)(xp + k0);
    v4h xh = { (_Float16)xv.x, (_Float16)xv.y, (_Float16)xv.z, (_Float16)xv.w };
    *(v4h*)&sA[bA * 40 + kqA * 4] = xh;
#pragma unroll
    for (int c = 0; c < 4; ++c)
      *(v8h*)&sB[tid * 40 + c * 8] = *(const v8h*)(wp + k0 + c * 8);
    __syncthreads();
#pragma unroll
    for (int mi = 0; mi < 4; ++mi) {
      v8h a = *(const v8h*)&sA[(16 * mi + l15) * 40 + kb * 8];
#pragma unroll
      for (int ni = 0; ni < 4; ++ni) {
        v8h b = *(const v8h*)&sB[(64 * w + 16 * ni + l15) * 40 + kb * 8];
        acc[mi][ni] = __builtin_amdgcn_mfma_f32_16x16x32_f16(a, b, acc[mi][ni], 0, 0, 0);
      }
    }
    __syncthreads();
  }

#pragma unroll
  for (int hh2 = 0; hh2 < 2; ++hh2) {
    __syncthreads();
    if ((w >> 2) == hh2) {
      int wl = w & 3;
#pragma unroll
      for (int ni = 0; ni < 4; ++ni) {
        int nloc = 64 * wl + 16 * ni + l15;
        int n = 256 * hh2 + nloc;
        float bia = bih0[n] + bhh0[n];
#pragma unroll
        for (int mi = 0; mi < 4; ++mi)
#pragma unroll
          for (int r = 0; r < 4; ++r)
            sC[nloc * 72 + 16 * mi + 4 * kb + r] = (_Float16)(acc[mi][ni][r] + bia);
      }
    }
    __syncthreads();
    int row = tid >> 1, part = tid & 1;
    _Float16* po = pre0 + ((long)t * G4 + 256 * hh2 + row) * 64 + part * 32;
#pragma unroll
    for (int c = 0; c < 4; ++c)
      *(v8h*)(po + c * 8) = *(const v8h*)&sC[row * 72 + part * 32 + c * 8];
  }
}

// ---------------- persistent pipelined LSTM, chunked handoff ----------------
// 160 blocks (layer l, batch-group bg). 8 waves; wave w owns j-strip [16w,16w+16)
// for all 4 gates; weights resident in registers. Cross-layer handoff every CK
// steps through an RC-chunk ring in LLC (sc0 sc1), flag-gated.
__global__ __launch_bounds__(512, 2) void lstm_pipe(
    const _Float16* __restrict__ pre0, const _Float16* __restrict__ Wc,
    const float* __restrict__ biasc, _Float16* __restrict__ yring,
    unsigned* __restrict__ flags, float* __restrict__ out)
{
  // LDS: y chunk tile [CK][rows 16(8 valid)][128h] swizzled = 32KB, h ping-pong [2][16][128h] = 8KB
  __shared__ __align__(16) unsigned char lds[40960];
  const int l = blockIdx.x >> 3, bg = blockIdx.x & 7;
  const int tid = threadIdx.x, w = tid >> 6, lane = tid & 63;
  const int l15 = lane & 15, kb = lane >> 4;
  const int jloc = 16 * w + l15;
  const bool valid = (kb < 2);
  const int b0 = 4 * (kb & 1);

  // weight fragments resident for the whole kernel
  v8h bw[4][8];
  const _Float16* wbase = Wc + (long)l * G4 * 256;
#pragma unroll
  for (int q = 0; q < 4; ++q)
#pragma unroll
    for (int ks = 0; ks < 8; ++ks)
      bw[q][ks] = *(const v8h*)(wbase + (long)(128 * q + jloc) * 256 + ks * 32 + kb * 8);

  float bias_q[4];
#pragma unroll
  for (int q = 0; q < 4; ++q)
    bias_q[q] = (l == 0) ? 0.0f : biasc[l * G4 + 128 * q + jloc];

  // zero h ping-pong buffers (512 threads x 16B = 8KB)
  *(v4u*)(lds + 32768 + tid * 16) = (v4u){0u, 0u, 0u, 0u};

  const int myf = l * 8 + bg;
  const unsigned* fin  = flags + ((l > 0) ? (myf - 8) : myf);
  const unsigned* fout = flags + ((l < NL - 1) ? (myf + 8) : myf);
  unsigned* fme = flags + myf;
  _Float16* ywr = yring + (long)myf * (RC * CK * 1024);
  const _Float16* yrd = yring + (long)(myf - 8) * (RC * CK * 1024);

  v4f cst = (v4f){0.f, 0.f, 0.f, 0.f};
  v4h pc[4];
  if (l == 0) {
    const _Float16* pb = pre0 + bg * 8 + b0;
#pragma unroll
    for (int q = 0; q < 4; ++q)
      pc[q] = *(const v4h*)(pb + (long)(128 * q + jloc) * 64);
  }

  __syncthreads();

  for (int c = 0; c < NCH; ++c) {
    if (l > 0) {
      // wait for producer chunk c (all lanes poll; LLC-coherent load)
      unsigned f;
      for (;;) {
        asm volatile("global_load_dword %0, %1, off sc0 sc1\n\ts_waitcnt vmcnt(0)"
                     : "=v"(f) : "v"(fin));
        if (f > (unsigned)c) break;
        __builtin_amdgcn_s_sleep(2);
      }
      // bulk-load chunk (32KB): thread -> tile t'=tid>>5, 64B at (tid&31)*64
      const _Float16* src = yrd + ((long)(c & (RC - 1)) * CK + (tid >> 5)) * 1024 + (tid & 31) * 32;
      v4u d0, d1, d2, d3;
      asm volatile("global_load_dwordx4 %0, %4, off sc0 sc1\n\t"
                   "global_load_dwordx4 %1, %4, off offset:16 sc0 sc1\n\t"
                   "global_load_dwordx4 %2, %4, off offset:32 sc0 sc1\n\t"
                   "global_load_dwordx4 %3, %4, off offset:48 sc0 sc1\n\t"
                   "s_waitcnt vmcnt(0)"
                   : "=v"(d0), "=v"(d1), "=v"(d2), "=v"(d3) : "v"(src));
      // transpose [j][b] -> LDS [b][j] (swizzled)
      unsigned char* tb = lds + (tid >> 5) * 2048;
      const int j0 = (tid & 31) * 4;
      union { v4u u; _Float16 h[8]; } qq;
#pragma unroll
      for (int jj = 0; jj < 4; ++jj) {
        qq.u = (jj == 0) ? d0 : (jj == 1) ? d1 : (jj == 2) ? d2 : d3;
#pragma unroll
        for (int b = 0; b < 8; ++b)
          *(_Float16*)(tb + swz(b, (j0 + jj) * 2)) = qq.h[b];
      }
    }
    if (l < NL - 1 && c >= RC) {
      // backpressure: ring slot (c mod RC) must be consumed (consumer flag >= c-1)
      unsigned f;
      for (;;) {
        asm volatile("global_load_dword %0, %1, off sc0 sc1\n\ts_waitcnt vmcnt(0)"
                     : "=v"(f) : "v"(fout));
        if (f >= (unsigned)(c - 1)) break;
        __builtin_amdgcn_s_sleep(2);
      }
    }
    __syncthreads();

    for (int ts = 0; ts < CK; ++ts) {
      const int t = c * CK + ts;
      const int p = t & 1;
      v4f acc[4];
#pragma unroll
      for (int q = 0; q < 4; ++q)
        acc[q] = (v4f){bias_q[q], bias_q[q], bias_q[q], bias_q[q]};

      v4h pn[4];
      if (l == 0) {
#pragma unroll
        for (int q = 0; q < 4; ++q)
#pragma unroll
          for (int r = 0; r < 4; ++r) acc[q][r] += (float)pc[q][r];
        // prefetch next step's pre0 (hides LLC latency under this step)
        const int tn = (t + 1) & (TT - 1);
        const _Float16* pb = pre0 + (long)tn * G4 * 64 + bg * 8 + b0;
#pragma unroll
        for (int q = 0; q < 4; ++q)
          pn[q] = *(const v4h*)(pb + (long)(128 * q + jloc) * 64);
      }

      const unsigned char* hb = lds + 32768 + p * 4096;
      if (l > 0) {
        const unsigned char* yb = lds + ts * 2048;
#pragma unroll
        for (int ks = 0; ks < 4; ++ks) {
          v8h a = *(const v8h*)(yb + swz(l15, ks * 64 + kb * 16));
#pragma unroll
          for (int q = 0; q < 4; ++q)
            acc[q] = __builtin_amdgcn_mfma_f32_16x16x32_f16(a, bw[q][ks], acc[q], 0, 0, 0);
        }
      }
#pragma unroll
      for (int ks = 4; ks < 8; ++ks) {
        v8h a = *(const v8h*)(hb + swz(l15, (ks - 4) * 64 + kb * 16));
#pragma unroll
        for (int q = 0; q < 4; ++q)
          acc[q] = __builtin_amdgcn_mfma_f32_16x16x32_f16(a, bw[q][ks], acc[q], 0, 0, 0);
      }

      _Float16 hh[4]; float hf[4];
#pragma unroll
      for (int r = 0; r < 4; ++r) {
        float i_ = fast_sig(acc[0][r]);
        float f_ = fast_sig(acc[1][r]);
        float g_ = fast_tanh(acc[2][r]);
        float o_ = fast_sig(acc[3][r]);
        float cn = f_ * cst[r] + i_ * g_;
        cst[r] = cn;
        float h_ = o_ * fast_tanh(cn);
        hf[r] = h_; hh[r] = (_Float16)h_;
      }

      if (valid) {
        unsigned char* hn = lds + 32768 + (p ^ 1) * 4096;
#pragma unroll
        for (int r = 0; r < 4; ++r)
          *(_Float16*)(hn + swz(b0 + r, jloc * 2)) = hh[r];
        if (l < NL - 1) {
          union { v2u u; _Float16 h[4]; } pk;
#pragma unroll
          for (int r = 0; r < 4; ++r) pk.h[r] = hh[r];
          _Float16* dst = ywr + ((long)(c & (RC - 1)) * CK + ts) * 1024 + jloc * 8 + b0;
          asm volatile("global_store_dwordx2 %0, %1, off sc0 sc1" :: "v"(dst), "v"(pk.u));
        } else if (t == TT - 1) {
#pragma unroll
          for (int r = 0; r < 4; ++r)
            out[(bg * 8 + b0 + r) * H4 + jloc] = hf[r];
        }
      }
      if (l == 0) {
#pragma unroll
        for (int q = 0; q < 4; ++q) pc[q] = pn[q];
      }
      __syncthreads();
    }

    // publish chunk c (stores drained on every wave before flag)
    asm volatile("s_waitcnt vmcnt(0)" ::: "memory");
    __syncthreads();
    if (tid == 0) {
      unsigned v = (unsigned)(c + 1);
      asm volatile("global_store_dword %0, %1, off sc0 sc1" :: "v"(fme), "v"(v) : "memory");
    }
  }
}

extern "C" void kernel_launch(void* const* d_in, const int* in_sizes, int n_in,
                              void* d_out, int out_size, void* d_ws, size_t ws_size,
                              hipStream_t stream)
{
  const float* x    = (const float*)d_in[0];
  const float* Wih0 = (const float*)d_in[1];
  const float* Whh0 = (const float*)d_in[2];
  const float* bih0 = (const float*)d_in[3];
  const float* bhh0 = (const float*)d_in[4];
  const float* Wih  = (const float*)d_in[5];
  const float* Whh  = (const float*)d_in[6];
  const float* bih  = (const float*)d_in[7];
  const float* bhh  = (const float*)d_in[8];
  float* out = (float*)d_out;
  char* ws = (char*)d_ws;

  _Float16* pre0  = (_Float16*)(ws);              // 33,554,432 B
  _Float16* W0h   = (_Float16*)(ws + 33554432);   //    786,432 B
  _Float16* Wc    = (_Float16*)(ws + 34340864);   //  5,242,880 B
  float*    bc    = (float*)   (ws + 39583744);   //     40,960 B
  _Float16* yring = (_Float16*)(ws + 39624704);   // 10,485,760 B (160 flows x RC x CK x 1024 x 2B)
  unsigned* flags = (unsigned*)(ws + 50110464);   //      1,024 B

  prep_kernel<<<11817, 256, 0, stream>>>(Wih0, Whh0, bih, bhh, Wih, Whh, W0h, Wc, bc, flags);
  pre0_gemm<<<TT, 512, 0, stream>>>(x, W0h, bih0, bhh0, pre0);
  lstm_pipe<<<NL * NBG, 512, 0, stream>>>(pre0, Wc, bc, yring, flags, out);
}